// Round 2
// baseline (390.372 us; speedup 1.0000x reference)
//
#include <hip/hip_runtime.h>

// CTC greedy decode: B=1024, T=512, C=128, blank=C-1.
// One block per batch row, 512 threads (8 waves), 2 blocks/CU.
// Stage 1: tile 128 timesteps into padded LDS (coalesced float4 global loads,
//          register-prefetched across tiles); 4 lanes per timestep do an
//          in-register argmax over 32 classes each, then a 2-step DPP
//          quad-shuffle reduce. First-occurrence tie-break throughout.
// Stage 2: collapse repeats + drop blanks via block prefix scan, scatter into
//          LDS char row, coalesced int32 store. (Validated absmax 0.)

constexpr int T_DIM   = 512;
constexpr int C_DIM   = 128;
constexpr int BLANK   = C_DIM - 1;
constexpr int BLOCK   = 512;
constexpr int TILE_T  = 128;                 // timesteps per LDS tile
constexpr int N_TILES = T_DIM / TILE_T;      // 4
constexpr int ROW_W   = 132;                 // padded words per timestep row
                                             // (128+4: keeps both ds_write_b128
                                             // staging and 4-lane reads at the
                                             // 8clk/KB LDS minimum)
constexpr int LDS_TILE_WORDS = TILE_T * ROW_W;  // 16896 words = 67.6 KB

__global__ __launch_bounds__(BLOCK, 4) void ctc_decode_kernel(
    const float* __restrict__ probs,
    const int* __restrict__ table,
    const int* __restrict__ defc_p,
    int* __restrict__ out)
{
    __shared__ float s_tile[LDS_TILE_WORDS];
    __shared__ int s_best[T_DIM];
    __shared__ int s_chars[T_DIM];
    __shared__ int s_table[C_DIM];
    __shared__ int s_wavesums[BLOCK / 64];

    const int b    = blockIdx.x;
    const int tid  = threadIdx.x;
    const int lane = tid & 63;
    const int wave = tid >> 6;

    if (tid < C_DIM) s_table[tid] = table[tid];
    const int defc = defc_p[0];

    const float* row = probs + (size_t)b * T_DIM * C_DIM;

    // ---- Stage 1: per-timestep argmax via LDS tiles ----
    const int ts = tid >> 2;   // timestep within tile owned by this thread's quad
    const int q  = tid & 3;    // quarter of the class dim (32 classes each)

    float4 pf[8];
    {   // prefetch tile 0: 4096 float4s, 8 per thread, fully coalesced
        const float4* src = (const float4*)row;
        #pragma unroll
        for (int j = 0; j < 8; ++j) pf[j] = src[j * BLOCK + tid];
    }

    for (int tile = 0; tile < N_TILES; ++tile) {
        __syncthreads();   // prior tile's LDS readers done before overwrite
        #pragma unroll
        for (int j = 0; j < 8; ++j) {
            const int idx4 = j * BLOCK + tid;       // float4 index within tile
            const int wts  = idx4 >> 5;             // timestep row
            const int m    = idx4 & 31;             // float4 slot within row
            *(float4*)&s_tile[wts * ROW_W + m * 4] = pf[j];
        }
        __syncthreads();   // staged writes visible

        if (tile + 1 < N_TILES) {  // issue next tile's loads; overlap argmax
            const float4* src = (const float4*)(row + (size_t)(tile + 1) * TILE_T * C_DIM);
            #pragma unroll
            for (int j = 0; j < 8; ++j) pf[j] = src[j * BLOCK + tid];
        }

        // In-register argmax over this quad-lane's 32 classes (ascending order,
        // strict > keeps first occurrence).
        const float* base = &s_tile[ts * ROW_W + q * 32];
        float bv = -1.0f; int bi = 0;
        #pragma unroll
        for (int k = 0; k < 8; ++k) {
            const float4 v = *(const float4*)(base + 4 * k);
            const int i0 = q * 32 + 4 * k;
            if (v.x > bv) { bv = v.x; bi = i0;     }
            if (v.y > bv) { bv = v.y; bi = i0 + 1; }
            if (v.z > bv) { bv = v.z; bi = i0 + 2; }
            if (v.w > bv) { bv = v.w; bi = i0 + 3; }
        }
        // Reduce across the 4 quad lanes (masks 1,2 -> DPP quad_perm, no LDS).
        #pragma unroll
        for (int m = 1; m <= 2; m <<= 1) {
            const float ov = __shfl_xor(bv, m);
            const int   oi = __shfl_xor(bi, m);
            if (ov > bv || (ov == bv && oi < bi)) { bv = ov; bi = oi; }
        }
        if (q == 0) s_best[tile * TILE_T + ts] = bi;
    }
    __syncthreads();

    // ---- Stage 2: valid mask + block inclusive scan ----
    const int best_t = s_best[tid];
    const int prev   = (tid > 0) ? s_best[tid - 1] : -1;
    const int valid  = (best_t != prev && best_t != BLANK) ? 1 : 0;

    int scan = valid;
    #pragma unroll
    for (int off = 1; off < 64; off <<= 1) {
        const int v = __shfl_up(scan, off);
        if (lane >= off) scan += v;
    }
    if (lane == 63) s_wavesums[wave] = scan;
    __syncthreads();
    if (tid == 0) {
        int acc = 0;
        #pragma unroll
        for (int w = 0; w < BLOCK / 64; ++w) {
            const int tmp = s_wavesums[w];
            s_wavesums[w] = acc;
            acc += tmp;
        }
    }
    __syncthreads();
    const int pos = scan + s_wavesums[wave] - 1;  // exclusive position among valid

    // ---- Scatter chars into LDS row, then coalesced store ----
    s_chars[tid] = defc;
    __syncthreads();
    if (valid) s_chars[pos] = s_table[best_t];
    __syncthreads();
    out[(size_t)b * T_DIM + tid] = s_chars[tid];
}

extern "C" void kernel_launch(void* const* d_in, const int* in_sizes, int n_in,
                              void* d_out, int out_size, void* d_ws, size_t ws_size,
                              hipStream_t stream) {
    const float* probs = (const float*)d_in[0];
    const int*   table = (const int*)d_in[1];
    const int*   defc  = (const int*)d_in[2];
    int*         out   = (int*)d_out;

    const int B = out_size / T_DIM;  // 1024
    ctc_decode_kernel<<<dim3(B), dim3(BLOCK), 0, stream>>>(probs, table, defc, out);
}

// Round 3
// 355.663 us; speedup vs baseline: 1.0976x; 1.0976x over previous
//
#include <hip/hip_runtime.h>

// CTC greedy decode: B=1024, T=512, C=128, blank=C-1.
// One block per batch row, 512 threads (8 waves), ~4.6 KB LDS (full occupancy).
//
// Stage 1 (argmax over C per timestep): 8 lanes per timestep, each lane owns
//   16 classes read directly from global as 4x float4 (each load instruction
//   covers 8 full 128-B lines -> perfectly coalesced, no LDS staging).
//   In-lane argmax (ascending index, strict > = first occurrence), then the
//   candidate is packed into a u64 key (value_bits<<32 | (127-idx)) -- inputs
//   are non-negative fp32 so bit patterns compare monotonically; key-max is
//   bit-exactly (max value, min index). 3-step __shfl_xor u64-max reduce.
//   Next iteration's loads are register-prefetched past the reduce chain.
//
// Stage 2 (collapse repeats + drop blanks): block prefix scan over valid
//   flags, scatter table[best] into LDS char row, coalesced int32 store.
//   (Validated absmax 0 in rounds 1-2; unchanged.)

constexpr int T_DIM = 512;
constexpr int C_DIM = 128;
constexpr int BLANK = C_DIM - 1;
constexpr int BLOCK = 512;
constexpr int TS_PER_ITER = BLOCK / 8;         // 64 timesteps per block-iteration
constexpr int N_ITER = T_DIM / TS_PER_ITER;    // 8

__global__ __launch_bounds__(BLOCK, 4) void ctc_decode_kernel(
    const float* __restrict__ probs,
    const int* __restrict__ table,
    const int* __restrict__ defc_p,
    int* __restrict__ out)
{
    __shared__ int s_best[T_DIM];
    __shared__ int s_chars[T_DIM];
    __shared__ int s_table[C_DIM];
    __shared__ int s_wavesums[BLOCK / 64];

    const int b    = blockIdx.x;
    const int tid  = threadIdx.x;
    const int lane = tid & 63;
    const int wave = tid >> 6;

    if (tid < C_DIM) s_table[tid] = table[tid];
    const int defc = defc_p[0];

    const float* row = probs + (size_t)b * T_DIM * C_DIM;

    // ---- Stage 1: per-timestep argmax, direct from global ----
    const int g = lane >> 3;   // timestep slot within this wave's group of 8
    const int h = lane & 7;    // lane within the timestep's 8-lane team

    float4 pf[4];
    {
        const float* p0 = row + (size_t)(wave * 8 + g) * C_DIM + h * 4;
        #pragma unroll
        for (int j = 0; j < 4; ++j) pf[j] = *(const float4*)(p0 + j * 32);
    }

    for (int it = 0; it < N_ITER; ++it) {
        float4 v[4];
        #pragma unroll
        for (int j = 0; j < 4; ++j) v[j] = pf[j];

        if (it + 1 < N_ITER) {  // prefetch next iteration past the reduce chain
            const float* pn = row + (size_t)((it + 1) * TS_PER_ITER + wave * 8 + g) * C_DIM + h * 4;
            #pragma unroll
            for (int j = 0; j < 4; ++j) pf[j] = *(const float4*)(pn + j * 32);
        }

        // In-lane argmax over this lane's 16 classes (indices ascend with j,
        // strict > keeps the first occurrence).
        float bv = -1.0f; int bi = 0;
        #pragma unroll
        for (int j = 0; j < 4; ++j) {
            const int i0 = j * 32 + h * 4;
            if (v[j].x > bv) { bv = v[j].x; bi = i0;     }
            if (v[j].y > bv) { bv = v[j].y; bi = i0 + 1; }
            if (v[j].z > bv) { bv = v[j].z; bi = i0 + 2; }
            if (v[j].w > bv) { bv = v[j].w; bi = i0 + 3; }
        }

        // Pack (value, first-index) into one monotonic u64 key.
        unsigned long long key =
            ((unsigned long long)__float_as_uint(bv) << 32) | (unsigned)(127 - bi);

        // Max-reduce across the 8-lane team (xor masks 1,2,4 stay in-team).
        #pragma unroll
        for (int m = 1; m <= 4; m <<= 1) {
            const unsigned long long ok = __shfl_xor(key, m);
            if (ok > key) key = ok;
        }

        if (h == 0) s_best[it * TS_PER_ITER + wave * 8 + g] = 127 - (int)(key & 127u);
    }
    __syncthreads();

    // ---- Stage 2: valid mask + block inclusive scan ----
    const int best_t = s_best[tid];
    const int prev   = (tid > 0) ? s_best[tid - 1] : -1;
    const int valid  = (best_t != prev && best_t != BLANK) ? 1 : 0;

    int scan = valid;
    #pragma unroll
    for (int off = 1; off < 64; off <<= 1) {
        const int vv = __shfl_up(scan, off);
        if (lane >= off) scan += vv;
    }
    if (lane == 63) s_wavesums[wave] = scan;
    __syncthreads();
    if (tid == 0) {
        int acc = 0;
        #pragma unroll
        for (int w = 0; w < BLOCK / 64; ++w) {
            const int tmp = s_wavesums[w];
            s_wavesums[w] = acc;
            acc += tmp;
        }
    }
    __syncthreads();
    const int pos = scan + s_wavesums[wave] - 1;  // exclusive position among valid

    // ---- Scatter chars into LDS row, then coalesced store ----
    s_chars[tid] = defc;
    __syncthreads();
    if (valid) s_chars[pos] = s_table[best_t];
    __syncthreads();
    out[(size_t)b * T_DIM + tid] = s_chars[tid];
}

extern "C" void kernel_launch(void* const* d_in, const int* in_sizes, int n_in,
                              void* d_out, int out_size, void* d_ws, size_t ws_size,
                              hipStream_t stream) {
    const float* probs = (const float*)d_in[0];
    const int*   table = (const int*)d_in[1];
    const int*   defc  = (const int*)d_in[2];
    int*         out   = (int*)d_out;

    const int B = out_size / T_DIM;  // 1024
    ctc_decode_kernel<<<dim3(B), dim3(BLOCK), 0, stream>>>(probs, table, defc, out);
}